// Round 14
// baseline (457.600 us; speedup 1.0000x reference)
//
#include <hip/hip_runtime.h>
#include <hip/hip_bf16.h>

#define B_ 2
#define H_ 32
#define HKV_ 8
#define T_ 1024
#define S_ 2048
#define DH_ 128
#define HD_ 4096      // H_*DH_
#define NROW_ 32768   // H_*T_
#define THRESH_D 0.000488

typedef __attribute__((ext_vector_type(4))) float f32x4;
typedef __attribute__((ext_vector_type(8))) short bf16x8;

#define SCHED0() __builtin_amdgcn_sched_barrier(0)

__device__ __forceinline__ void gload_lds16(const void* g, void* l) {
  __builtin_amdgcn_global_load_lds(
      (const __attribute__((address_space(1))) void*)g,
      (__attribute__((address_space(3))) void*)l, 16, 0, 0);
}

// ======== K2+K4 fused: reduce partials -> keep; wo f32 -> bf16 swizzled ========

__global__ void reduce_wo_k(const double* __restrict__ partial,
                            float* __restrict__ keep,
                            const float* __restrict__ w,
                            __hip_bfloat16* __restrict__ wb) {
  __shared__ double sh[4][64];
  if (blockIdx.x < 64) {
    int b = blockIdx.x >> 5;
    int s0 = (blockIdx.x & 31) * 64;
    int wv = threadIdx.x >> 6, l = threadIdx.x & 63;
    const double* p = partial + (size_t)b * 256 * S_ + s0 + l;
    double sum = 0.0;
    #pragma unroll 8
    for (int y = 0; y < 64; ++y) sum += p[(size_t)(wv * 64 + y) * S_];
    sh[wv][l] = sum;
    __syncthreads();
    if (wv == 0) {
      double t = (sh[0][l] + sh[1][l]) + (sh[2][l] + sh[3][l]);
      keep[b * S_ + s0 + l] = (t * (1.0 / 32768.0) > THRESH_D) ? 1.0f : 0.0f;
    }
  } else {
    size_t idx = ((size_t)(blockIdx.x - 64) * 256 + threadIdx.x) * 8;
    int n = (int)(idx >> 12);
    int k0 = (int)(idx & (HD_ - 1));
    float4 x = *(const float4*)(w + idx);
    float4 y = *(const float4*)(w + idx + 4);
    union { bf16x8 v8; __hip_bfloat16 h[8]; } u;
    u.h[0] = __float2bfloat16(x.x); u.h[1] = __float2bfloat16(x.y);
    u.h[2] = __float2bfloat16(x.z); u.h[3] = __float2bfloat16(x.w);
    u.h[4] = __float2bfloat16(y.x); u.h[5] = __float2bfloat16(y.y);
    u.h[6] = __float2bfloat16(y.z); u.h[7] = __float2bfloat16(y.w);
    int ksw = (k0 & ~63) | ((k0 ^ ((n & 7) << 3)) & 63);
    *(bf16x8*)(wb + (size_t)n * HD_ + ksw) = u.v8;
  }
}

// ================= K6: GEMM2 out = ctx @ wo^T =================

#define BK2 64
#define NS2 64

__global__ __launch_bounds__(512) void gemm2_k(
    const __hip_bfloat16* __restrict__ Actx,
    const __hip_bfloat16* __restrict__ Bw,
    float* __restrict__ out) {
  __shared__ __align__(16) __hip_bfloat16 As[2][128 * BK2];
  __shared__ __align__(16) __hip_bfloat16 Bs[2][128 * BK2];
  int tid = threadIdx.x;
  int lg = ((blockIdx.x & 7) << 6) | (blockIdx.x >> 3);
  int n0 = (lg >> 4) * 128;
  int m0 = (lg & 15) * 128;
  const __hip_bfloat16* Ap = Actx + (size_t)m0 * HD_;
  const __hip_bfloat16* Bp = Bw + (size_t)n0 * HD_;
  int wave = tid >> 6, lane = tid & 63;
  int l16 = lane & 15, lk = lane >> 4;

  f32x4 acc[8];
  f32x4 z = {0.f, 0.f, 0.f, 0.f};
  #pragma unroll
  for (int n = 0; n < 8; ++n) acc[n] = z;

  auto issue = [&](int ks, int buf) {
    const __hip_bfloat16* ga = Ap + (size_t)(tid >> 3) * HD_ + ks * BK2 + (tid & 7) * 8;
    const __hip_bfloat16* gb = Bp + (size_t)(tid >> 3) * HD_ + ks * BK2 + (tid & 7) * 8;
    char* la = (char*)&As[buf][0] + tid * 16;
    char* lb = (char*)&Bs[buf][0] + tid * 16;
    gload_lds16(ga, la);
    gload_lds16(ga + (size_t)64 * HD_, la + 8192);
    gload_lds16(gb, lb);
    gload_lds16(gb + (size_t)64 * HD_, lb + 8192);
  };

  auto mfmaStep = [&](int buf) {
    char* ab = (char*)&As[buf][0];
    char* bb = (char*)&Bs[buf][0];
    #pragma unroll
    for (int kk = 0; kk < 2; ++kk) {
      int kb = kk * 64 + lk * 16;
      int ar = wave * 16 + l16;
      bf16x8 af = *(const bf16x8*)(ab + (ar * 128 + (kb ^ ((ar & 7) << 4))));
      #pragma unroll
      for (int n = 0; n < 8; ++n) {
        int br = n * 16 + l16;
        bf16x8 bf = *(const bf16x8*)(bb + (br * 128 + (kb ^ ((br & 7) << 4))));
        acc[n] = __builtin_amdgcn_mfma_f32_16x16x32_bf16(af, bf, acc[n], 0, 0, 0);
      }
    }
  };

  issue(0, 0);
  for (int ks = 0; ks < NS2; ++ks) {
    int cur = ks & 1;
    if (ks + 1 < NS2) issue(ks + 1, cur ^ 1);
    SCHED0();
    if (ks + 1 < NS2) {
      asm volatile("s_waitcnt vmcnt(4) lgkmcnt(0)" ::: "memory");
    } else {
      asm volatile("s_waitcnt vmcnt(0) lgkmcnt(0)" ::: "memory");
    }
    SCHED0();
    __builtin_amdgcn_s_barrier();
    SCHED0();
    mfmaStep(cur);
    SCHED0();
    __builtin_amdgcn_s_barrier();
    SCHED0();
  }

  #pragma unroll
  for (int n = 0; n < 8; ++n)
    #pragma unroll
    for (int r = 0; r < 4; ++r) {
      int row = m0 + wave * 16 + lk * 4 + r;
      int col = n0 + n * 16 + l16;
      out[(size_t)row * HD_ + col] = acc[n][r];
    }
}

// ================= PATH A (abf in workspace; needs >=336 MB) =================

__global__ __launch_bounds__(256) void colsumA_k(
    const float* __restrict__ attn, double* __restrict__ partial,
    __hip_bfloat16* __restrict__ abf) {
  int tid = threadIdx.x;
  int chunk = blockIdx.x;                        // 0..511
  size_t base = (size_t)chunk * 128 * S_;
  const float* ap = attn + base;
  __hip_bfloat16* ob = abf + base;
  double a0 = 0, a1 = 0, a2 = 0, a3 = 0;
  double b0 = 0, b1 = 0, b2 = 0, b3 = 0;
  #pragma unroll 4
  for (int i = 0; i < 256; ++i) {
    size_t off = (size_t)i * 1024 + tid * 4;
    f32x4 vv = *(const f32x4*)(ap + off);
    int row = i >> 1;
    int s = ((i & 1) << 10) + tid * 4;
    int ssw = (s & ~63) | ((s ^ ((row & 7) << 3)) & 63);
    union { ushort4 u4; __hip_bfloat16 h[4]; } u;
    u.h[0] = __float2bfloat16(vv.x); u.h[1] = __float2bfloat16(vv.y);
    u.h[2] = __float2bfloat16(vv.z); u.h[3] = __float2bfloat16(vv.w);
    *(ushort4*)(ob + (size_t)row * S_ + ssw) = u.u4;
    if (i & 1) { b0 += vv.x; b1 += vv.y; b2 += vv.z; b3 += vv.w; }
    else       { a0 += vv.x; a1 += vv.y; a2 += vv.z; a3 += vv.w; }
  }
  double* o = partial + (size_t)chunk * S_ + tid * 4;
  o[0] = a0; o[1] = a1; o[2] = a2; o[3] = a3;
  double* o2 = partial + (size_t)chunk * S_ + 1024 + tid * 4;
  o2[0] = b0; o2[1] = b1; o2[2] = b2; o2[3] = b3;
}

__global__ void convert_vA_k(const float* __restrict__ v,
                             const float* __restrict__ keep,
                             __hip_bfloat16* __restrict__ vt) {
  __shared__ float tile[32][33];
  int bh = blockIdx.z;
  int b = bh >> 3;
  int s0 = blockIdx.x * 32, d0 = blockIdx.y * 32;
  const float* vp = v + (size_t)bh * (S_ * DH_);
  __hip_bfloat16* vtp = vt + (size_t)bh * (S_ * DH_);
  int tx = threadIdx.x, ty = threadIdx.y;
  for (int i = 0; i < 32; i += 8)
    tile[ty + i][tx] = vp[(size_t)(s0 + ty + i) * DH_ + d0 + tx];
  __syncthreads();
  int s = s0 + tx;
  float kv = keep[b * S_ + s];
  for (int i = 0; i < 32; i += 8) {
    int d = d0 + ty + i;
    int ssw = (s & ~63) | ((s ^ ((d & 7) << 3)) & 63);
    vtp[(size_t)d * S_ + ssw] = __float2bfloat16(tile[tx][ty + i] * kv);
  }
}

#define BK1 64
#define NS1 32

// A-path de-LDS'd: MFMA af-fragments and prunedWrite sources load directly
// from pre-swizzled abf global into register banks (static two-bank, rule #20).
// LDS: Bs only (32 KB) + ksh (8 KB) -> 3 blocks/CU (was 2).
__global__ __launch_bounds__(512, 4) void prune_gemm1A_k(
    const __hip_bfloat16* __restrict__ abf, const float* __restrict__ keep,
    const __hip_bfloat16* __restrict__ vt, float* __restrict__ pruned,
    __hip_bfloat16* __restrict__ ctx) {
  __shared__ __align__(16) __hip_bfloat16 Bs[2][128 * BK1];
  __shared__ __align__(16) float ksh[S_];

  int tid = threadIdx.x;
  int lg = ((blockIdx.x & 7) << 6) | (blockIdx.x >> 3);
  int bh = lg >> 3;
  int t0 = (lg & 7) * 128;
  int b = bh >> 5, h = bh & 31, hkv = h >> 2;
  int rot = (lg * 17) & 31;
  const char* Ab = (const char*)(abf + ((size_t)bh * T_ + t0) * S_);
  float* P = pruned + ((size_t)bh * T_ + t0) * S_;
  const __hip_bfloat16* Bv = vt + (size_t)(b * HKV_ + hkv) * (DH_ * S_);
  const float* kp = keep + b * S_;

  int wave = tid >> 6, lane = tid & 63;
  int l16 = lane & 15, lk = lane >> 4;
  int ar = wave * 16 + l16;                 // MFMA A row (0..127)
  int prow = tid >> 3;                      // prunedWrite row (0..63, +64)
  int afoff0 = (lk * 16) ^ ((ar & 7) << 4);         // byte off in 128B K-row
  int afoff1 = (64 + lk * 16) ^ ((ar & 7) << 4);
  int pwoff = (tid & 7) * 16;

  f32x4 acc[8];
  f32x4 z = {0.f, 0.f, 0.f, 0.f};
  #pragma unroll
  for (int n = 0; n < 8; ++n) acc[n] = z;

  bf16x8 afA0, afA1, pwA0, pwA1;
  bf16x8 afB0, afB1, pwB0, pwB1;

  auto col = [&](int j) { return (j + rot) & 31; };

  auto issueB = [&](int cks, int buf) {  // 2 gload_lds
    const __hip_bfloat16* g0 = Bv + (size_t)(tid >> 3) * S_ + cks * BK1 + (tid & 7) * 8;
    char* lb = (char*)&Bs[buf][0] + tid * 16;
    gload_lds16(g0, lb);
    gload_lds16(g0 + (size_t)64 * S_, lb + 8192);
  };

  auto prefA = [&](int cks, bf16x8& a0, bf16x8& a1, bf16x8& p0, bf16x8& p1) {
    const char* tb = Ab + (size_t)cks * 128;
    a0 = *(const bf16x8*)(tb + (size_t)ar * (2 * S_) + afoff0);
    a1 = *(const bf16x8*)(tb + (size_t)ar * (2 * S_) + afoff1);
    p0 = *(const bf16x8*)(tb + (size_t)prow * (2 * S_) + pwoff);
    p1 = *(const bf16x8*)(tb + (size_t)(prow + 64) * (2 * S_) + pwoff);
  };

  auto mfmaStep = [&](int buf, bf16x8 a0, bf16x8 a1) {
    char* bb = (char*)&Bs[buf][0];
    #pragma unroll
    for (int kk = 0; kk < 2; ++kk) {
      int kb = kk * 64 + lk * 16;
      bf16x8 af = kk ? a1 : a0;
      #pragma unroll
      for (int n = 0; n < 8; ++n) {
        int br = n * 16 + l16;
        bf16x8 bf = *(const bf16x8*)(bb + (br * 128 + (kb ^ ((br & 7) << 4))));
        acc[n] = __builtin_amdgcn_mfma_f32_16x16x32_bf16(af, bf, acc[n], 0, 0, 0);
      }
    }
  };

  auto prunedWrite = [&](int cks, bf16x8 p0v, bf16x8 p1v) {
    union { bf16x8 v; unsigned int d[4]; } u0, u1;
    u0.v = p0v; u1.v = p1v;
    int scol = cks * BK1 + (((tid & 7) * 8) ^ ((prow & 7) << 3));
    f32x4 k0 = *(const f32x4*)&ksh[scol];
    f32x4 k1 = *(const f32x4*)&ksh[scol + 4];
    f32x4 p00, p01, p10, p11;
    p00.x = __uint_as_float(u0.d[0] << 16) * k0.x;
    p00.y = __uint_as_float(u0.d[0] & 0xFFFF0000u) * k0.y;
    p00.z = __uint_as_float(u0.d[1] << 16) * k0.z;
    p00.w = __uint_as_float(u0.d[1] & 0xFFFF0000u) * k0.w;
    p01.x = __uint_as_float(u0.d[2] << 16) * k1.x;
    p01.y = __uint_as_float(u0.d[2] & 0xFFFF0000u) * k1.y;
    p01.z = __uint_as_float(u0.d[3] << 16) * k1.z;
    p01.w = __uint_as_float(u0.d[3] & 0xFFFF0000u) * k1.w;
    p10.x = __uint_as_float(u1.d[0] << 16) * k0.x;
    p10.y = __uint_as_float(u1.d[0] & 0xFFFF0000u) * k0.y;
    p10.z = __uint_as_float(u1.d[1] << 16) * k0.z;
    p10.w = __uint_as_float(u1.d[1] & 0xFFFF0000u) * k0.w;
    p11.x = __uint_as_float(u1.d[2] << 16) * k1.x;
    p11.y = __uint_as_float(u1.d[2] & 0xFFFF0000u) * k1.y;
    p11.z = __uint_as_float(u1.d[3] << 16) * k1.z;
    p11.w = __uint_as_float(u1.d[3] & 0xFFFF0000u) * k1.w;
    float* gp0 = P + (size_t)prow * S_ + scol;
    float* gp1 = P + (size_t)(prow + 64) * S_ + scol;
    *(f32x4*)gp0 = p00; *(f32x4*)(gp0 + 4) = p01;
    *(f32x4*)gp1 = p10; *(f32x4*)(gp1 + 4) = p11;
  };

  // Prologue: ksh(1) | B0(2) | prefA0(4)
  gload_lds16(kp + tid * 4, (char*)ksh + tid * 16);
  issueB(col(0), 0);
  SCHED0();
  prefA(col(0), afA0, afA1, pwA0, pwA1);
  SCHED0();
  asm volatile("s_waitcnt vmcnt(6)" ::: "memory");  // ksh retired
  SCHED0();
  __builtin_amdgcn_s_barrier();                     // ksh visible
  SCHED0();

  for (int ks = 0; ks < NS1; ks += 2) {
    { // even: buf0, bank A; prefetch bank B for ks+1
      if (ks + 1 < NS1) issueB(col(ks + 1), 1);
      SCHED0();
      if (ks + 1 < NS1) prefA(col(ks + 1), afB0, afB1, pwB0, pwB1);
      SCHED0();
      // need B(ks) retired; newer ops (in issue order after B(ks)):
      //   ks==0: prefA0(4)+B1(2)+prefB1(4)=10
      //   else : prefB(prev)(4)+stores(prev)(4)+B(ks+1)(2)+prefB(4)=14
      if (ks == 0) { asm volatile("s_waitcnt vmcnt(10) lgkmcnt(0)" ::: "memory"); }
      else         { asm volatile("s_waitcnt vmcnt(14) lgkmcnt(0)" ::: "memory"); }
      SCHED0();
      __builtin_amdgcn_s_barrier();
      SCHED0();
      mfmaStep(0, afA0, afA1);
      prunedWrite(col(ks), pwA0, pwA1);
      SCHED0();
      __builtin_amdgcn_s_barrier();
      SCHED0();
    }
    { // odd: buf1, bank B; prefetch bank A for ko+1
      int ko = ks + 1;
      if (ko + 1 < NS1) issueB(col(ko + 1), 0);
      SCHED0();
      if (ko + 1 < NS1) prefA(col(ko + 1), afA0, afA1, pwA0, pwA1);
      SCHED0();
      // need B(ko) retired; newer: prefB(4)+stores(4)[+B(2)+prefA(4) if issued]
      if (ko + 1 < NS1) { asm volatile("s_waitcnt vmcnt(14) lgkmcnt(0)" ::: "memory"); }
      else              { asm volatile("s_waitcnt vmcnt(8) lgkmcnt(0)" ::: "memory"); }
      SCHED0();
      __builtin_amdgcn_s_barrier();
      SCHED0();
      mfmaStep(1, afB0, afB1);
      prunedWrite(col(ko), pwB0, pwB1);
      SCHED0();
      __builtin_amdgcn_s_barrier();
      SCHED0();
    }
  }

  // ctx write: [B*T][HD], pre-swizzled for GEMM2's A staging
  #pragma unroll
  for (int n = 0; n < 8; ++n)
    #pragma unroll
    for (int r = 0; r < 4; ++r) {
      int trow = t0 + wave * 16 + lk * 4 + r;
      int rowm = b * T_ + trow;
      int kcol = h * DH_ + n * 16 + l16;
      int ksw = (kcol & ~63) | ((kcol ^ ((rowm & 7) << 3)) & 63);
      ctx[(size_t)rowm * HD_ + ksw] = __float2bfloat16(acc[n][r]);
    }
}

// ================= PATH B (no abf; fallback) =================

__global__ __launch_bounds__(256) void colsumB_k(
    const float* __restrict__ attn, double* __restrict__ partial) {
  int tid = threadIdx.x;
  int chunk = blockIdx.x;
  size_t base = (size_t)chunk * 128 * S_;
  const float* ap = attn + base;
  double a0 = 0, a1 = 0, a2 = 0, a3 = 0;
  double b0 = 0, b1 = 0, b2 = 0, b3 = 0;
  #pragma unroll 4
  for (int i = 0; i < 256; ++i) {
    size_t off = (size_t)i * 1024 + tid * 4;
    f32x4 vv = *(const f32x4*)(ap + off);
    if (i & 1) { b0 += vv.x; b1 += vv.y; b2 += vv.z; b3 += vv.w; }
    else       { a0 += vv.x; a1 += vv.y; a2 += vv.z; a3 += vv.w; }
  }
  double* o = partial + (size_t)chunk * S_ + tid * 4;
  o[0] = a0; o[1] = a1; o[2] = a2; o[3] = a3;
  double* o2 = partial + (size_t)chunk * S_ + 1024 + tid * 4;
  o2[0] = b0; o2[1] = b1; o2[2] = b2; o2[3] = b3;
}

__global__ void convert_vB_k(const float* __restrict__ v,
                             __hip_bfloat16* __restrict__ vt) {
  __shared__ float tile[32][33];
  int bh = blockIdx.z;
  int s0 = blockIdx.x * 32, d0 = blockIdx.y * 32;
  const float* vp = v + (size_t)bh * (S_ * DH_);
  __hip_bfloat16* vtp = vt + (size_t)bh * (S_ * DH_);
  int tx = threadIdx.x, ty = threadIdx.y;
  for (int i = 0; i < 32; i += 8)
    tile[ty + i][tx] = vp[(size_t)(s0 + ty + i) * DH_ + d0 + tx];
  __syncthreads();
  int s = s0 + tx;
  for (int i = 0; i < 32; i += 8) {
    int d = d0 + ty + i;
    int ssw = (s & ~63) | ((s ^ ((d & 7) << 3)) & 63);
    vtp[(size_t)d * S_ + ssw] = __float2bfloat16(tile[tx][ty + i]);
  }
}

__global__ __launch_bounds__(512, 4) void prune_gemm1B_k(
    const float* __restrict__ attn, const float* __restrict__ keep,
    const __hip_bfloat16* __restrict__ vt, float* __restrict__ pruned,
    __hip_bfloat16* __restrict__ ctx) {
  __shared__ __align__(16) __hip_bfloat16 As[2][128 * BK1];
  __shared__ __align__(16) __hip_bfloat16 Bs[2][128 * BK1];
  __shared__ __align__(16) float ksh[S_];

  int tid = threadIdx.x;
  int lg = ((blockIdx.x & 7) << 6) | (blockIdx.x >> 3);
  int bh = lg >> 3;
  int t0 = (lg & 7) * 128;
  int b = bh >> 5, h = bh & 31, hkv = h >> 2;
  int rot = (lg * 17) & 31;
  const float* A = attn + ((size_t)bh * T_ + t0) * S_;
  float* P = pruned + ((size_t)bh * T_ + t0) * S_;
  const __hip_bfloat16* Bv = vt + (size_t)(b * HKV_ + hkv) * (DH_ * S_);
  const float* kp = keep + b * S_;

  int arow = tid >> 2;
  int acol = (tid & 3) * 16;
  int wave = tid >> 6, lane = tid & 63;
  int l16 = lane & 15, lk = lane >> 4;

  f32x4 acc[8];
  f32x4 z = {0.f, 0.f, 0.f, 0.f};
  #pragma unroll
  for (int n = 0; n < 8; ++n) acc[n] = z;

  f32x4 areg0[4], areg1[4];

  auto col = [&](int j) { return (j + rot) & 31; };

  auto issueA = [&](int cks, f32x4* bank) {
    const float* ga = A + (size_t)arow * S_ + cks * BK1 + acol;
    #pragma unroll
    for (int j = 0; j < 4; ++j) bank[j] = *(const f32x4*)(ga + j * 4);
  };

  auto issueB = [&](int cks, int buf) {
    const __hip_bfloat16* g0 = Bv + (size_t)(tid >> 3) * S_ + cks * BK1 + (tid & 7) * 8;
    char* lb = (char*)&Bs[buf][0] + tid * 16;
    gload_lds16(g0, lb);
    gload_lds16(g0 + (size_t)64 * S_, lb + 8192);
  };

  auto stageA = [&](int cks, int buf, const f32x4* bank) {
    f32x4 p[4];
    #pragma unroll
    for (int j = 0; j < 4; ++j) {
      f32x4 kv = *(const f32x4*)&ksh[cks * BK1 + acol + j * 4];
      p[j] = bank[j] * kv;
    }
    float* gp = P + (size_t)arow * S_ + cks * BK1 + acol;
    #pragma unroll
    for (int j = 0; j < 4; ++j) *(f32x4*)(gp + j * 4) = p[j];
    union { bf16x8 v8; __hip_bfloat16 h[8]; } u0, u1;
    const float* pf = (const float*)&p[0];
    #pragma unroll
    for (int j = 0; j < 8; ++j) u0.h[j] = __float2bfloat16(pf[j]);
    #pragma unroll
    for (int j = 0; j < 8; ++j) u1.h[j] = __float2bfloat16(pf[8 + j]);
    char* ab = (char*)&As[buf][0];
    int base0 = arow * 128 + acol * 2;
    int sw = (arow & 7) << 4;
    *(bf16x8*)(ab + (base0 ^ sw)) = u0.v8;
    *(bf16x8*)(ab + ((base0 + 16) ^ sw)) = u1.v8;
  };

  auto mfmaStep = [&](int buf) {
    char* ab = (char*)&As[buf][0];
    char* bb = (char*)&Bs[buf][0];
    #pragma unroll
    for (int kk = 0; kk < 2; ++kk) {
      int kb = kk * 64 + lk * 16;
      int ar = wave * 16 + l16;
      bf16x8 af = *(const bf16x8*)(ab + (ar * 128 + (kb ^ ((ar & 7) << 4))));
      #pragma unroll
      for (int n = 0; n < 8; ++n) {
        int br = n * 16 + l16;
        bf16x8 bf = *(const bf16x8*)(bb + (br * 128 + (kb ^ ((br & 7) << 4))));
        acc[n] = __builtin_amdgcn_mfma_f32_16x16x32_bf16(af, bf, acc[n], 0, 0, 0);
      }
    }
  };

  gload_lds16(kp + tid * 4, (char*)ksh + tid * 16);
  issueB(col(0), 0);
  issueA(col(0), areg0);
  SCHED0();
  asm volatile("s_waitcnt vmcnt(6)" ::: "memory");
  SCHED0();
  __builtin_amdgcn_s_barrier();
  SCHED0();
  issueA(col(1), areg1);
  stageA(col(0), 0, areg0);

  for (int ks = 0; ks < NS1; ks += 2) {
    {
      if (ks + 1 < NS1) issueB(col(ks + 1), 1);
      if (ks + 2 < NS1) issueA(col(ks + 2), areg0);
      if (ks + 1 < NS1) stageA(col(ks + 1), 1, areg1);
      SCHED0();
      if (ks + 2 < NS1)      { asm volatile("s_waitcnt vmcnt(18) lgkmcnt(0)" ::: "memory"); }
      else if (ks + 1 < NS1) { asm volatile("s_waitcnt vmcnt(14) lgkmcnt(0)" ::: "memory"); }
      else                   { asm volatile("s_waitcnt vmcnt(4) lgkmcnt(0)" ::: "memory"); }
      SCHED0();
      __builtin_amdgcn_s_barrier();
      SCHED0();
      mfmaStep(0);
      SCHED0();
      __builtin_amdgcn_s_barrier();
      SCHED0();
    }
    {
      int ko = ks + 1;
      if (ko + 1 < NS1) issueB(col(ko + 1), 0);
      if (ko + 2 < NS1) issueA(col(ko + 2), areg1);
      if (ko + 1 < NS1) stageA(col(ko + 1), 0, areg0);
      SCHED0();
      if (ko + 2 < NS1)      { asm volatile("s_waitcnt vmcnt(18) lgkmcnt(0)" ::: "memory"); }
      else if (ko + 1 < NS1) { asm volatile("s_waitcnt vmcnt(14) lgkmcnt(0)" ::: "memory"); }
      else                   { asm volatile("s_waitcnt vmcnt(4) lgkmcnt(0)" ::: "memory"); }
      SCHED0();
      __builtin_amdgcn_s_barrier();
      SCHED0();
      mfmaStep(1);
      SCHED0();
      __builtin_amdgcn_s_barrier();
      SCHED0();
    }
  }

  #pragma unroll
  for (int n = 0; n < 8; ++n)
    #pragma unroll
    for (int r = 0; r < 4; ++r) {
      int trow = t0 + wave * 16 + lk * 4 + r;
      int rowm = b * T_ + trow;
      int kcol = h * DH_ + n * 16 + l16;
      int ksw = (kcol & ~63) | ((kcol ^ ((rowm & 7) << 3)) & 63);
      ctx[(size_t)rowm * HD_ + ksw] = __float2bfloat16(acc[n][r]);
    }
}

// ================= launcher =================

extern "C" void kernel_launch(void* const* d_in, const int* in_sizes, int n_in,
                              void* d_out, int out_size, void* d_ws, size_t ws_size,
                              hipStream_t stream) {
  const float* attn = (const float*)d_in[0];
  const float* v = (const float*)d_in[1];
  const float* w_o = (const float*)d_in[2];
  float* out = (float*)d_out;
  float* pruned = out + (size_t)B_ * T_ * HD_;

  char* ws = (char*)d_ws;
  size_t off = 0;
  double* partial = (double*)(ws + off); off += (size_t)B_ * 256 * S_ * 8;   // 8 MB
  float* keep = (float*)(ws + off);      off += (size_t)B_ * S_ * 4;         // 16 KB
  __hip_bfloat16* vt = (__hip_bfloat16*)(ws + off);
  off += (size_t)B_ * HKV_ * DH_ * S_ * 2;                                   // 8 MB
  __hip_bfloat16* wo = (__hip_bfloat16*)(ws + off);
  off += (size_t)HD_ * HD_ * 2;                                              // 32 MB
  __hip_bfloat16* ctx = (__hip_bfloat16*)(ws + off);
  off += (size_t)B_ * T_ * HD_ * 2;                                          // 16 MB
  __hip_bfloat16* abf = (__hip_bfloat16*)(ws + off);
  size_t need_abf = off + (size_t)B_ * NROW_ * S_ * 2;                       // +256 MB

  bool bigws = (ws_size >= need_abf);
  int wo_grid = 64 + (HD_ * HD_) / (256 * 8);

  if (bigws) {
    colsumA_k<<<dim3(512), 256, 0, stream>>>(attn, partial, abf);
    reduce_wo_k<<<dim3(wo_grid), 256, 0, stream>>>(partial, keep, w_o, wo);
    convert_vA_k<<<dim3(S_ / 32, DH_ / 32, B_ * HKV_), dim3(32, 8), 0, stream>>>(v, keep, vt);
    prune_gemm1A_k<<<dim3(512), 512, 0, stream>>>(abf, keep, vt, pruned, ctx);
  } else {
    colsumB_k<<<dim3(512), 256, 0, stream>>>(attn, partial);
    reduce_wo_k<<<dim3(wo_grid), 256, 0, stream>>>(partial, keep, w_o, wo);
    convert_vB_k<<<dim3(S_ / 32, DH_ / 32, B_ * HKV_), dim3(32, 8), 0, stream>>>(v, vt);
    prune_gemm1B_k<<<dim3(512), 512, 0, stream>>>(attn, keep, vt, pruned, ctx);
  }
  gemm2_k<<<dim3(512), 512, 0, stream>>>(ctx, wo, out);

  (void)in_sizes; (void)n_in; (void)out_size; (void)ws_size;
}

// Round 15
// 448.487 us; speedup vs baseline: 1.0203x; 1.0203x over previous
//
#include <hip/hip_runtime.h>
#include <hip/hip_bf16.h>

#define B_ 2
#define H_ 32
#define HKV_ 8
#define T_ 1024
#define S_ 2048
#define DH_ 128
#define HD_ 4096      // H_*DH_
#define NROW_ 32768   // H_*T_
#define THRESH_D 0.000488

typedef __attribute__((ext_vector_type(4))) float f32x4;
typedef __attribute__((ext_vector_type(8))) short bf16x8;

#define SCHED0() __builtin_amdgcn_sched_barrier(0)

__device__ __forceinline__ void gload_lds16(const void* g, void* l) {
  __builtin_amdgcn_global_load_lds(
      (const __attribute__((address_space(1))) void*)g,
      (__attribute__((address_space(3))) void*)l, 16, 0, 0);
}

// ======== K2+K4 fused: reduce partials -> keep; wo f32 -> bf16 swizzled ========

__global__ void reduce_wo_k(const double* __restrict__ partial,
                            float* __restrict__ keep,
                            const float* __restrict__ w,
                            __hip_bfloat16* __restrict__ wb) {
  __shared__ double sh[4][64];
  if (blockIdx.x < 64) {
    int b = blockIdx.x >> 5;
    int s0 = (blockIdx.x & 31) * 64;
    int wv = threadIdx.x >> 6, l = threadIdx.x & 63;
    const double* p = partial + (size_t)b * 256 * S_ + s0 + l;
    double sum = 0.0;
    #pragma unroll 8
    for (int y = 0; y < 64; ++y) sum += p[(size_t)(wv * 64 + y) * S_];
    sh[wv][l] = sum;
    __syncthreads();
    if (wv == 0) {
      double t = (sh[0][l] + sh[1][l]) + (sh[2][l] + sh[3][l]);
      keep[b * S_ + s0 + l] = (t * (1.0 / 32768.0) > THRESH_D) ? 1.0f : 0.0f;
    }
  } else {
    size_t idx = ((size_t)(blockIdx.x - 64) * 256 + threadIdx.x) * 8;
    int n = (int)(idx >> 12);
    int k0 = (int)(idx & (HD_ - 1));
    float4 x = *(const float4*)(w + idx);
    float4 y = *(const float4*)(w + idx + 4);
    union { bf16x8 v8; __hip_bfloat16 h[8]; } u;
    u.h[0] = __float2bfloat16(x.x); u.h[1] = __float2bfloat16(x.y);
    u.h[2] = __float2bfloat16(x.z); u.h[3] = __float2bfloat16(x.w);
    u.h[4] = __float2bfloat16(y.x); u.h[5] = __float2bfloat16(y.y);
    u.h[6] = __float2bfloat16(y.z); u.h[7] = __float2bfloat16(y.w);
    int ksw = (k0 & ~63) | ((k0 ^ ((n & 7) << 3)) & 63);
    *(bf16x8*)(wb + (size_t)n * HD_ + ksw) = u.v8;
  }
}

// ================= K6: GEMM2 out = ctx @ wo^T =================

#define BK2 64
#define NS2 64

__global__ __launch_bounds__(512) void gemm2_k(
    const __hip_bfloat16* __restrict__ Actx,
    const __hip_bfloat16* __restrict__ Bw,
    float* __restrict__ out) {
  __shared__ __align__(16) __hip_bfloat16 As[2][128 * BK2];
  __shared__ __align__(16) __hip_bfloat16 Bs[2][128 * BK2];
  int tid = threadIdx.x;
  int lg = ((blockIdx.x & 7) << 6) | (blockIdx.x >> 3);
  int n0 = (lg >> 4) * 128;
  int m0 = (lg & 15) * 128;
  const __hip_bfloat16* Ap = Actx + (size_t)m0 * HD_;
  const __hip_bfloat16* Bp = Bw + (size_t)n0 * HD_;
  int wave = tid >> 6, lane = tid & 63;
  int l16 = lane & 15, lk = lane >> 4;

  f32x4 acc[8];
  f32x4 z = {0.f, 0.f, 0.f, 0.f};
  #pragma unroll
  for (int n = 0; n < 8; ++n) acc[n] = z;

  auto issue = [&](int ks, int buf) {
    const __hip_bfloat16* ga = Ap + (size_t)(tid >> 3) * HD_ + ks * BK2 + (tid & 7) * 8;
    const __hip_bfloat16* gb = Bp + (size_t)(tid >> 3) * HD_ + ks * BK2 + (tid & 7) * 8;
    char* la = (char*)&As[buf][0] + tid * 16;
    char* lb = (char*)&Bs[buf][0] + tid * 16;
    gload_lds16(ga, la);
    gload_lds16(ga + (size_t)64 * HD_, la + 8192);
    gload_lds16(gb, lb);
    gload_lds16(gb + (size_t)64 * HD_, lb + 8192);
  };

  auto mfmaStep = [&](int buf) {
    char* ab = (char*)&As[buf][0];
    char* bb = (char*)&Bs[buf][0];
    #pragma unroll
    for (int kk = 0; kk < 2; ++kk) {
      int kb = kk * 64 + lk * 16;
      int ar = wave * 16 + l16;
      bf16x8 af = *(const bf16x8*)(ab + (ar * 128 + (kb ^ ((ar & 7) << 4))));
      #pragma unroll
      for (int n = 0; n < 8; ++n) {
        int br = n * 16 + l16;
        bf16x8 bf = *(const bf16x8*)(bb + (br * 128 + (kb ^ ((br & 7) << 4))));
        acc[n] = __builtin_amdgcn_mfma_f32_16x16x32_bf16(af, bf, acc[n], 0, 0, 0);
      }
    }
  };

  issue(0, 0);
  for (int ks = 0; ks < NS2; ++ks) {
    int cur = ks & 1;
    if (ks + 1 < NS2) issue(ks + 1, cur ^ 1);
    SCHED0();
    if (ks + 1 < NS2) {
      asm volatile("s_waitcnt vmcnt(4) lgkmcnt(0)" ::: "memory");
    } else {
      asm volatile("s_waitcnt vmcnt(0) lgkmcnt(0)" ::: "memory");
    }
    SCHED0();
    __builtin_amdgcn_s_barrier();
    SCHED0();
    mfmaStep(cur);
    SCHED0();
    __builtin_amdgcn_s_barrier();
    SCHED0();
  }

  #pragma unroll
  for (int n = 0; n < 8; ++n)
    #pragma unroll
    for (int r = 0; r < 4; ++r) {
      int row = m0 + wave * 16 + lk * 4 + r;
      int col = n0 + n * 16 + l16;
      out[(size_t)row * HD_ + col] = acc[n][r];
    }
}

// ================= PATH A (abf in workspace; needs >=336 MB) =================

__global__ __launch_bounds__(256) void colsumA_k(
    const float* __restrict__ attn, double* __restrict__ partial,
    __hip_bfloat16* __restrict__ abf) {
  int tid = threadIdx.x;
  int chunk = blockIdx.x;                        // 0..511
  size_t base = (size_t)chunk * 128 * S_;
  const float* ap = attn + base;
  __hip_bfloat16* ob = abf + base;
  double a0 = 0, a1 = 0, a2 = 0, a3 = 0;
  double b0 = 0, b1 = 0, b2 = 0, b3 = 0;
  #pragma unroll 4
  for (int i = 0; i < 256; ++i) {
    size_t off = (size_t)i * 1024 + tid * 4;
    f32x4 vv = *(const f32x4*)(ap + off);
    int row = i >> 1;
    int s = ((i & 1) << 10) + tid * 4;
    int ssw = (s & ~63) | ((s ^ ((row & 7) << 3)) & 63);
    union { ushort4 u4; __hip_bfloat16 h[4]; } u;
    u.h[0] = __float2bfloat16(vv.x); u.h[1] = __float2bfloat16(vv.y);
    u.h[2] = __float2bfloat16(vv.z); u.h[3] = __float2bfloat16(vv.w);
    *(ushort4*)(ob + (size_t)row * S_ + ssw) = u.u4;
    if (i & 1) { b0 += vv.x; b1 += vv.y; b2 += vv.z; b3 += vv.w; }
    else       { a0 += vv.x; a1 += vv.y; a2 += vv.z; a3 += vv.w; }
  }
  double* o = partial + (size_t)chunk * S_ + tid * 4;
  o[0] = a0; o[1] = a1; o[2] = a2; o[3] = a3;
  double* o2 = partial + (size_t)chunk * S_ + 1024 + tid * 4;
  o2[0] = b0; o2[1] = b1; o2[2] = b2; o2[3] = b3;
}

__global__ void convert_vA_k(const float* __restrict__ v,
                             const float* __restrict__ keep,
                             __hip_bfloat16* __restrict__ vt) {
  __shared__ float tile[32][33];
  int bh = blockIdx.z;
  int b = bh >> 3;
  int s0 = blockIdx.x * 32, d0 = blockIdx.y * 32;
  const float* vp = v + (size_t)bh * (S_ * DH_);
  __hip_bfloat16* vtp = vt + (size_t)bh * (S_ * DH_);
  int tx = threadIdx.x, ty = threadIdx.y;
  for (int i = 0; i < 32; i += 8)
    tile[ty + i][tx] = vp[(size_t)(s0 + ty + i) * DH_ + d0 + tx];
  __syncthreads();
  int s = s0 + tx;
  float kv = keep[b * S_ + s];
  for (int i = 0; i < 32; i += 8) {
    int d = d0 + ty + i;
    int ssw = (s & ~63) | ((s ^ ((d & 7) << 3)) & 63);
    vtp[(size_t)d * S_ + ssw] = __float2bfloat16(tile[tx][ty + i] * kv);
  }
}

#define BK1 64
#define NS1 32

__global__ __launch_bounds__(512, 4) void prune_gemm1A_k(
    const __hip_bfloat16* __restrict__ abf, const float* __restrict__ keep,
    const __hip_bfloat16* __restrict__ vt, float* __restrict__ pruned,
    __hip_bfloat16* __restrict__ ctx) {
  __shared__ __align__(16) __hip_bfloat16 As[2][128 * BK1];
  __shared__ __align__(16) __hip_bfloat16 Bs[2][128 * BK1];
  __shared__ __align__(16) float ksh[S_];

  int tid = threadIdx.x;
  int lg = ((blockIdx.x & 7) << 6) | (blockIdx.x >> 3);
  int bh = lg >> 3;
  int t0 = (lg & 7) * 128;
  int b = bh >> 5, h = bh & 31, hkv = h >> 2;
  int rot = (lg * 17) & 31;
  const __hip_bfloat16* Ab = abf + ((size_t)bh * T_ + t0) * S_;
  float* P = pruned + ((size_t)bh * T_ + t0) * S_;
  const __hip_bfloat16* Bv = vt + (size_t)(b * HKV_ + hkv) * (DH_ * S_);
  const float* kp = keep + b * S_;

  int wave = tid >> 6, lane = tid & 63;
  int l16 = lane & 15, lk = lane >> 4;

  f32x4 acc[8];
  f32x4 z = {0.f, 0.f, 0.f, 0.f};
  #pragma unroll
  for (int n = 0; n < 8; ++n) acc[n] = z;

  auto col = [&](int j) { return (j + rot) & 31; };

  auto issueA = [&](int cks, int buf) {
    const __hip_bfloat16* g0 = Ab + (size_t)(tid >> 3) * S_ + cks * BK1 + (tid & 7) * 8;
    char* la = (char*)&As[buf][0] + tid * 16;
    gload_lds16(g0, la);
    gload_lds16(g0 + (size_t)64 * S_, la + 8192);
  };

  auto issueB = [&](int cks, int buf) {
    const __hip_bfloat16* g0 = Bv + (size_t)(tid >> 3) * S_ + cks * BK1 + (tid & 7) * 8;
    char* lb = (char*)&Bs[buf][0] + tid * 16;
    gload_lds16(g0, lb);
    gload_lds16(g0 + (size_t)64 * S_, lb + 8192);
  };

  auto mfmaStep = [&](int buf) {
    char* ab = (char*)&As[buf][0];
    char* bb = (char*)&Bs[buf][0];
    #pragma unroll
    for (int kk = 0; kk < 2; ++kk) {
      int kb = kk * 64 + lk * 16;
      int ar = wave * 16 + l16;
      bf16x8 af = *(const bf16x8*)(ab + (ar * 128 + (kb ^ ((ar & 7) << 4))));
      #pragma unroll
      for (int n = 0; n < 8; ++n) {
        int br = n * 16 + l16;
        bf16x8 bf = *(const bf16x8*)(bb + (br * 128 + (kb ^ ((br & 7) << 4))));
        acc[n] = __builtin_amdgcn_mfma_f32_16x16x32_bf16(af, bf, acc[n], 0, 0, 0);
      }
    }
  };

  auto prunedWrite = [&](int cks, int buf) {
    char* ab = (char*)&As[buf][0];
    union { bf16x8 v; unsigned int d[4]; } u0, u1;
    u0.v = *(const bf16x8*)(ab + tid * 16);
    u1.v = *(const bf16x8*)(ab + tid * 16 + 8192);
    int row0 = tid >> 3;
    int scol = cks * BK1 + (((tid & 7) * 8) ^ ((row0 & 7) << 3));
    f32x4 k0 = *(const f32x4*)&ksh[scol];
    f32x4 k1 = *(const f32x4*)&ksh[scol + 4];
    f32x4 p00, p01, p10, p11;
    p00.x = __uint_as_float(u0.d[0] << 16) * k0.x;
    p00.y = __uint_as_float(u0.d[0] & 0xFFFF0000u) * k0.y;
    p00.z = __uint_as_float(u0.d[1] << 16) * k0.z;
    p00.w = __uint_as_float(u0.d[1] & 0xFFFF0000u) * k0.w;
    p01.x = __uint_as_float(u0.d[2] << 16) * k1.x;
    p01.y = __uint_as_float(u0.d[2] & 0xFFFF0000u) * k1.y;
    p01.z = __uint_as_float(u0.d[3] << 16) * k1.z;
    p01.w = __uint_as_float(u0.d[3] & 0xFFFF0000u) * k1.w;
    p10.x = __uint_as_float(u1.d[0] << 16) * k0.x;
    p10.y = __uint_as_float(u1.d[0] & 0xFFFF0000u) * k0.y;
    p10.z = __uint_as_float(u1.d[1] << 16) * k0.z;
    p10.w = __uint_as_float(u1.d[1] & 0xFFFF0000u) * k0.w;
    p11.x = __uint_as_float(u1.d[2] << 16) * k1.x;
    p11.y = __uint_as_float(u1.d[2] & 0xFFFF0000u) * k1.y;
    p11.z = __uint_as_float(u1.d[3] << 16) * k1.z;
    p11.w = __uint_as_float(u1.d[3] & 0xFFFF0000u) * k1.w;
    float* gp0 = P + (size_t)row0 * S_ + scol;
    float* gp1 = P + (size_t)(row0 + 64) * S_ + scol;
    *(f32x4*)gp0 = p00; *(f32x4*)(gp0 + 4) = p01;
    *(f32x4*)gp1 = p10; *(f32x4*)(gp1 + 4) = p11;
  };

  gload_lds16(kp + tid * 4, (char*)ksh + tid * 16);
  issueA(col(0), 0);
  issueB(col(0), 0);
  SCHED0();
  asm volatile("s_waitcnt vmcnt(4)" ::: "memory");
  SCHED0();
  __builtin_amdgcn_s_barrier();
  SCHED0();

  for (int ks = 0; ks < NS1; ++ks) {
    int cur = ks & 1;
    if (ks + 1 < NS1) {
      issueA(col(ks + 1), cur ^ 1);
      issueB(col(ks + 1), cur ^ 1);
    }
    SCHED0();
    if (ks == 0 || ks == NS1 - 1) {
      asm volatile("s_waitcnt vmcnt(4) lgkmcnt(0)" ::: "memory");
    } else {
      asm volatile("s_waitcnt vmcnt(8) lgkmcnt(0)" ::: "memory");
    }
    SCHED0();
    __builtin_amdgcn_s_barrier();
    SCHED0();
    mfmaStep(cur);
    prunedWrite(col(ks), cur);   // after MFMA: drains in MFMA's shadow
    SCHED0();
    __builtin_amdgcn_s_barrier();
    SCHED0();
  }

  #pragma unroll
  for (int n = 0; n < 8; ++n)
    #pragma unroll
    for (int r = 0; r < 4; ++r) {
      int trow = t0 + wave * 16 + lk * 4 + r;
      int rowm = b * T_ + trow;
      int kcol = h * DH_ + n * 16 + l16;
      int ksw = (kcol & ~63) | ((kcol ^ ((rowm & 7) << 3)) & 63);
      ctx[(size_t)rowm * HD_ + ksw] = __float2bfloat16(acc[n][r]);
    }
}

// ================= PATH B (no abf; fallback) =================

__global__ __launch_bounds__(256) void colsumB_k(
    const float* __restrict__ attn, double* __restrict__ partial) {
  int tid = threadIdx.x;
  int chunk = blockIdx.x;
  size_t base = (size_t)chunk * 128 * S_;
  const float* ap = attn + base;
  double a0 = 0, a1 = 0, a2 = 0, a3 = 0;
  double b0 = 0, b1 = 0, b2 = 0, b3 = 0;
  #pragma unroll 4
  for (int i = 0; i < 256; ++i) {
    size_t off = (size_t)i * 1024 + tid * 4;
    f32x4 vv = *(const f32x4*)(ap + off);
    if (i & 1) { b0 += vv.x; b1 += vv.y; b2 += vv.z; b3 += vv.w; }
    else       { a0 += vv.x; a1 += vv.y; a2 += vv.z; a3 += vv.w; }
  }
  double* o = partial + (size_t)chunk * S_ + tid * 4;
  o[0] = a0; o[1] = a1; o[2] = a2; o[3] = a3;
  double* o2 = partial + (size_t)chunk * S_ + 1024 + tid * 4;
  o2[0] = b0; o2[1] = b1; o2[2] = b2; o2[3] = b3;
}

__global__ void convert_vB_k(const float* __restrict__ v,
                             __hip_bfloat16* __restrict__ vt) {
  __shared__ float tile[32][33];
  int bh = blockIdx.z;
  int s0 = blockIdx.x * 32, d0 = blockIdx.y * 32;
  const float* vp = v + (size_t)bh * (S_ * DH_);
  __hip_bfloat16* vtp = vt + (size_t)bh * (S_ * DH_);
  int tx = threadIdx.x, ty = threadIdx.y;
  for (int i = 0; i < 32; i += 8)
    tile[ty + i][tx] = vp[(size_t)(s0 + ty + i) * DH_ + d0 + tx];
  __syncthreads();
  int s = s0 + tx;
  for (int i = 0; i < 32; i += 8) {
    int d = d0 + ty + i;
    int ssw = (s & ~63) | ((s ^ ((d & 7) << 3)) & 63);
    vtp[(size_t)d * S_ + ssw] = __float2bfloat16(tile[tx][ty + i]);
  }
}

__global__ __launch_bounds__(512, 4) void prune_gemm1B_k(
    const float* __restrict__ attn, const float* __restrict__ keep,
    const __hip_bfloat16* __restrict__ vt, float* __restrict__ pruned,
    __hip_bfloat16* __restrict__ ctx) {
  __shared__ __align__(16) __hip_bfloat16 As[2][128 * BK1];
  __shared__ __align__(16) __hip_bfloat16 Bs[2][128 * BK1];
  __shared__ __align__(16) float ksh[S_];

  int tid = threadIdx.x;
  int lg = ((blockIdx.x & 7) << 6) | (blockIdx.x >> 3);
  int bh = lg >> 3;
  int t0 = (lg & 7) * 128;
  int b = bh >> 5, h = bh & 31, hkv = h >> 2;
  int rot = (lg * 17) & 31;
  const float* A = attn + ((size_t)bh * T_ + t0) * S_;
  float* P = pruned + ((size_t)bh * T_ + t0) * S_;
  const __hip_bfloat16* Bv = vt + (size_t)(b * HKV_ + hkv) * (DH_ * S_);
  const float* kp = keep + b * S_;

  int arow = tid >> 2;
  int acol = (tid & 3) * 16;
  int wave = tid >> 6, lane = tid & 63;
  int l16 = lane & 15, lk = lane >> 4;

  f32x4 acc[8];
  f32x4 z = {0.f, 0.f, 0.f, 0.f};
  #pragma unroll
  for (int n = 0; n < 8; ++n) acc[n] = z;

  f32x4 areg0[4], areg1[4];

  auto col = [&](int j) { return (j + rot) & 31; };

  auto issueA = [&](int cks, f32x4* bank) {
    const float* ga = A + (size_t)arow * S_ + cks * BK1 + acol;
    #pragma unroll
    for (int j = 0; j < 4; ++j) bank[j] = *(const f32x4*)(ga + j * 4);
  };

  auto issueB = [&](int cks, int buf) {
    const __hip_bfloat16* g0 = Bv + (size_t)(tid >> 3) * S_ + cks * BK1 + (tid & 7) * 8;
    char* lb = (char*)&Bs[buf][0] + tid * 16;
    gload_lds16(g0, lb);
    gload_lds16(g0 + (size_t)64 * S_, lb + 8192);
  };

  auto stageA = [&](int cks, int buf, const f32x4* bank) {
    f32x4 p[4];
    #pragma unroll
    for (int j = 0; j < 4; ++j) {
      f32x4 kv = *(const f32x4*)&ksh[cks * BK1 + acol + j * 4];
      p[j] = bank[j] * kv;
    }
    float* gp = P + (size_t)arow * S_ + cks * BK1 + acol;
    #pragma unroll
    for (int j = 0; j < 4; ++j) *(f32x4*)(gp + j * 4) = p[j];
    union { bf16x8 v8; __hip_bfloat16 h[8]; } u0, u1;
    const float* pf = (const float*)&p[0];
    #pragma unroll
    for (int j = 0; j < 8; ++j) u0.h[j] = __float2bfloat16(pf[j]);
    #pragma unroll
    for (int j = 0; j < 8; ++j) u1.h[j] = __float2bfloat16(pf[8 + j]);
    char* ab = (char*)&As[buf][0];
    int base0 = arow * 128 + acol * 2;
    int sw = (arow & 7) << 4;
    *(bf16x8*)(ab + (base0 ^ sw)) = u0.v8;
    *(bf16x8*)(ab + ((base0 + 16) ^ sw)) = u1.v8;
  };

  auto mfmaStep = [&](int buf) {
    char* ab = (char*)&As[buf][0];
    char* bb = (char*)&Bs[buf][0];
    #pragma unroll
    for (int kk = 0; kk < 2; ++kk) {
      int kb = kk * 64 + lk * 16;
      int ar = wave * 16 + l16;
      bf16x8 af = *(const bf16x8*)(ab + (ar * 128 + (kb ^ ((ar & 7) << 4))));
      #pragma unroll
      for (int n = 0; n < 8; ++n) {
        int br = n * 16 + l16;
        bf16x8 bf = *(const bf16x8*)(bb + (br * 128 + (kb ^ ((br & 7) << 4))));
        acc[n] = __builtin_amdgcn_mfma_f32_16x16x32_bf16(af, bf, acc[n], 0, 0, 0);
      }
    }
  };

  gload_lds16(kp + tid * 4, (char*)ksh + tid * 16);
  issueB(col(0), 0);
  issueA(col(0), areg0);
  SCHED0();
  asm volatile("s_waitcnt vmcnt(6)" ::: "memory");
  SCHED0();
  __builtin_amdgcn_s_barrier();
  SCHED0();
  issueA(col(1), areg1);
  stageA(col(0), 0, areg0);

  for (int ks = 0; ks < NS1; ks += 2) {
    {
      if (ks + 1 < NS1) issueB(col(ks + 1), 1);
      if (ks + 2 < NS1) issueA(col(ks + 2), areg0);
      if (ks + 1 < NS1) stageA(col(ks + 1), 1, areg1);
      SCHED0();
      if (ks + 2 < NS1)      { asm volatile("s_waitcnt vmcnt(18) lgkmcnt(0)" ::: "memory"); }
      else if (ks + 1 < NS1) { asm volatile("s_waitcnt vmcnt(14) lgkmcnt(0)" ::: "memory"); }
      else                   { asm volatile("s_waitcnt vmcnt(4) lgkmcnt(0)" ::: "memory"); }
      SCHED0();
      __builtin_amdgcn_s_barrier();
      SCHED0();
      mfmaStep(0);
      SCHED0();
      __builtin_amdgcn_s_barrier();
      SCHED0();
    }
    {
      int ko = ks + 1;
      if (ko + 1 < NS1) issueB(col(ko + 1), 0);
      if (ko + 2 < NS1) issueA(col(ko + 2), areg1);
      if (ko + 1 < NS1) stageA(col(ko + 1), 0, areg0);
      SCHED0();
      if (ko + 2 < NS1)      { asm volatile("s_waitcnt vmcnt(18) lgkmcnt(0)" ::: "memory"); }
      else if (ko + 1 < NS1) { asm volatile("s_waitcnt vmcnt(14) lgkmcnt(0)" ::: "memory"); }
      else                   { asm volatile("s_waitcnt vmcnt(4) lgkmcnt(0)" ::: "memory"); }
      SCHED0();
      __builtin_amdgcn_s_barrier();
      SCHED0();
      mfmaStep(1);
      SCHED0();
      __builtin_amdgcn_s_barrier();
      SCHED0();
    }
  }

  #pragma unroll
  for (int n = 0; n < 8; ++n)
    #pragma unroll
    for (int r = 0; r < 4; ++r) {
      int trow = t0 + wave * 16 + lk * 4 + r;
      int rowm = b * T_ + trow;
      int kcol = h * DH_ + n * 16 + l16;
      int ksw = (kcol & ~63) | ((kcol ^ ((rowm & 7) << 3)) & 63);
      ctx[(size_t)rowm * HD_ + ksw] = __float2bfloat16(acc[n][r]);
    }
}

// ================= launcher =================

extern "C" void kernel_launch(void* const* d_in, const int* in_sizes, int n_in,
                              void* d_out, int out_size, void* d_ws, size_t ws_size,
                              hipStream_t stream) {
  const float* attn = (const float*)d_in[0];
  const float* v = (const float*)d_in[1];
  const float* w_o = (const float*)d_in[2];
  float* out = (float*)d_out;
  float* pruned = out + (size_t)B_ * T_ * HD_;

  char* ws = (char*)d_ws;
  size_t off = 0;
  double* partial = (double*)(ws + off); off += (size_t)B_ * 256 * S_ * 8;   // 8 MB
  float* keep = (float*)(ws + off);      off += (size_t)B_ * S_ * 4;         // 16 KB
  __hip_bfloat16* vt = (__hip_bfloat16*)(ws + off);
  off += (size_t)B_ * HKV_ * DH_ * S_ * 2;                                   // 8 MB
  __hip_bfloat16* wo = (__hip_bfloat16*)(ws + off);
  off += (size_t)HD_ * HD_ * 2;                                              // 32 MB
  __hip_bfloat16* ctx = (__hip_bfloat16*)(ws + off);
  off += (size_t)B_ * T_ * HD_ * 2;                                          // 16 MB
  __hip_bfloat16* abf = (__hip_bfloat16*)(ws + off);
  size_t need_abf = off + (size_t)B_ * NROW_ * S_ * 2;                       // +256 MB

  bool bigws = (ws_size >= need_abf);
  int wo_grid = 64 + (HD_ * HD_) / (256 * 8);

  if (bigws) {
    colsumA_k<<<dim3(512), 256, 0, stream>>>(attn, partial, abf);
    reduce_wo_k<<<dim3(wo_grid), 256, 0, stream>>>(partial, keep, w_o, wo);
    convert_vA_k<<<dim3(S_ / 32, DH_ / 32, B_ * HKV_), dim3(32, 8), 0, stream>>>(v, keep, vt);
    prune_gemm1A_k<<<dim3(512), 512, 0, stream>>>(abf, keep, vt, pruned, ctx);
  } else {
    colsumB_k<<<dim3(512), 256, 0, stream>>>(attn, partial);
    reduce_wo_k<<<dim3(wo_grid), 256, 0, stream>>>(partial, keep, w_o, wo);
    convert_vB_k<<<dim3(S_ / 32, DH_ / 32, B_ * HKV_), dim3(32, 8), 0, stream>>>(v, vt);
    prune_gemm1B_k<<<dim3(512), 512, 0, stream>>>(attn, keep, vt, pruned, ctx);
  }
  gemm2_k<<<dim3(512), 512, 0, stream>>>(ctx, wo, out);

  (void)in_sizes; (void)n_in; (void)out_size; (void)ws_size;
}